// Round 11
// baseline (260.466 us; speedup 1.0000x reference)
//
#include <hip/hip_runtime.h>
#include <hip/hip_bf16.h>
#include <cstdint>

#define B_N 16384
#define KN 64
#define DN 256
#define AN 64
#define ROWS 8

typedef float f32x4 __attribute__((ext_vector_type(4)));
typedef float f32x2 __attribute__((ext_vector_type(2)));
typedef short s16x8 __attribute__((ext_vector_type(8)));

// pack two f32 -> one u32 of 2x bf16 (RTN); .x lands in low 16 bits
static __device__ inline unsigned int pk2(float a, float b) {
    __hip_bfloat162 h = __float22bfloat162_rn(make_float2(a, b));
    return *reinterpret_cast<unsigned int*>(&h);
}
static __device__ inline float bf_lo(unsigned int v) { return __uint_as_float(v << 16); }
static __device__ inline float bf_hi(unsigned int v) { return __uint_as_float(v & 0xFFFF0000u); }

// ---------------------------------------------------------------------------
// K0: M = Wq^T @ Wk (256x256 f32)  and  Wgb = bf16(Wgate) ([256 out][512 in])
// ---------------------------------------------------------------------------
__global__ __launch_bounds__(256) void prep_kernel(const float* __restrict__ Wq,
                                                   const float* __restrict__ Wk,
                                                   const float* __restrict__ Wgate,
                                                   float* __restrict__ M,
                                                   unsigned int* __restrict__ Wgb) {
    int blk = blockIdx.x;
    int t = threadIdx.x;
    if (blk < DN) {
        float acc = 0.f;
        #pragma unroll
        for (int a = 0; a < AN; ++a)
            acc += Wq[a * DN + blk] * Wk[a * DN + t];
        M[blk * DN + t] = acc;
    } else {
        int d = blk - DN;                    // 0..255 output row
        const float* src = Wgate + (size_t)d * (2 * DN);
        Wgb[(size_t)d * 256 + t] = pk2(src[2 * t], src[2 * t + 1]);
    }
}

// ---------------------------------------------------------------------------
// K0b: qk = center @ M, output bf16 pairs [B][128 words] (8 MB).
// M fully L2-resident here (no competing stream). R2-verified tile.
// ---------------------------------------------------------------------------
__global__ __launch_bounds__(256) void qk_kernel(const float* __restrict__ center,
                                                 const float* __restrict__ M,
                                                 unsigned int* __restrict__ qkb) {
    __shared__ float xs[32 * DN];            // 32 KB
    int r0 = blockIdx.x * 32;
    int tid = threadIdx.x;

    const float4* src = (const float4*)(center + (size_t)r0 * DN);
    float4* dst = (float4*)xs;
    #pragma unroll
    for (int i = 0; i < 8; ++i)
        dst[tid + 256 * i] = src[tid + 256 * i];
    __syncthreads();

    int ty = tid >> 5, tx = tid & 31;
    float acc[4][8];
    #pragma unroll
    for (int r = 0; r < 4; ++r)
        #pragma unroll
        for (int c = 0; c < 8; ++c) acc[r][c] = 0.f;

    for (int k4 = 0; k4 < DN; k4 += 4) {
        float4 xr[4];
        #pragma unroll
        for (int r = 0; r < 4; ++r)
            xr[r] = *(const float4*)(&xs[(ty * 4 + r) * DN + k4]);
        #pragma unroll
        for (int kk = 0; kk < 4; ++kk) {
            float4 ma = *(const float4*)(&M[(size_t)(k4 + kk) * DN + tx * 8]);
            float4 mb = *(const float4*)(&M[(size_t)(k4 + kk) * DN + tx * 8 + 4]);
            #pragma unroll
            for (int r = 0; r < 4; ++r) {
                float x = (&xr[r].x)[kk];
                acc[r][0] += x * ma.x; acc[r][1] += x * ma.y;
                acc[r][2] += x * ma.z; acc[r][3] += x * ma.w;
                acc[r][4] += x * mb.x; acc[r][5] += x * mb.y;
                acc[r][6] += x * mb.z; acc[r][7] += x * mb.w;
            }
        }
    }
    #pragma unroll
    for (int r = 0; r < 4; ++r) {
        size_t row = (size_t)(r0 + ty * 4 + r);
        uint4 o;
        o.x = pk2(acc[r][0], acc[r][1]);
        o.y = pk2(acc[r][2], acc[r][3]);
        o.z = pk2(acc[r][4], acc[r][5]);
        o.w = pk2(acc[r][6], acc[r][7]);
        *(uint4*)&qkb[row * 128 + tx * 4] = o;
    }
}

// ---------------------------------------------------------------------------
// K1: attention. 2048 blocks x 8 rows, ~38.3 KB LDS, launch_bounds(256,2)
// (verified regime; tighter caps spilled in R8/R9). qkb precomputed
// (4 KB/block); attn never touches M. Row loop identical to R10's verified
// structure; ROWS=8 halves the per-block no-prefetch tail and prologue.
// ---------------------------------------------------------------------------
__global__ __launch_bounds__(256, 2) void attn_kernel(const float* __restrict__ neigh,
                                                      const unsigned int* __restrict__ qkb,
                                                      const float* __restrict__ ppi,
                                                      float* __restrict__ ctx) {
    __shared__ unsigned int sn[KN * 128];    // 32 KB current tile (bf16 pairs)
    __shared__ unsigned int sqk[ROWS * 128]; //  4 KB q rows (bf16 pairs)
    __shared__ float slog[KN];
    __shared__ float sattn[KN];
    __shared__ float scr[DN];                //  1 KB ctx k-half combine

    const int tid = threadIdx.x;
    const int lane = tid & 63;
    const int b0 = blockIdx.x * ROWS;

    // issue row-0 tile prefetch (nontemporal: one-touch stream)
    f32x4 rr[16];
    {
        const f32x4* t4 = (const f32x4*)(neigh + (size_t)b0 * (KN * DN));
        #pragma unroll
        for (int i = 0; i < 16; ++i)
            rr[i] = __builtin_nontemporal_load(t4 + tid + 256 * i);
    }

    // qk rows -> LDS (1024 words, one uint4 per thread)
    ((uint4*)sqk)[tid] = ((const uint4*)(qkb + (size_t)b0 * 128))[tid];

    // ppi rows -> registers (wave 0 uses them in softmax)
    float pv[ROWS];
    #pragma unroll
    for (int r = 0; r < ROWS; ++r) pv[r] = ppi[(size_t)(b0 + r) * KN + lane];

    #pragma unroll
    for (int r = 0; r < ROWS; ++r) {
        if (r > 0) __syncthreads();          // guard sn/scr overwrite vs prev reads

        // staged regs -> sn (bf16 pairs)
        {
            uint2* dst = (uint2*)sn;
            #pragma unroll
            for (int i = 0; i < 16; ++i)
                dst[tid + 256 * i] = make_uint2(pk2(rr[i].x, rr[i].y), pk2(rr[i].z, rr[i].w));
        }
        // prefetch next row's tile (in flight during this row's compute)
        if (r < ROWS - 1) {
            const f32x4* n4 = (const f32x4*)(neigh + (size_t)(b0 + r + 1) * (KN * DN));
            #pragma unroll
            for (int i = 0; i < 16; ++i)
                rr[i] = __builtin_nontemporal_load(n4 + tid + 256 * i);
        }
        __syncthreads();                      // sn (and for r=0: sqk) visible

        // logits: group g=tid>>2 owns k-row g; rotated d-walk (2-way banks)
        {
            const int g = tid >> 2, j = tid & 3;
            float acc = 0.f;
            #pragma unroll
            for (int m = 0; m < 32; ++m) {
                int s = (m + g) & 31;
                int p = j + 4 * s;            // pair index 0..127
                unsigned int nv = sn[g * 128 + p];
                unsigned int qv = sqk[r * 128 + p];
                acc += bf_lo(nv) * bf_lo(qv) + bf_hi(nv) * bf_hi(qv);
            }
            acc += __shfl_xor(acc, 1, 64);
            acc += __shfl_xor(acc, 2, 64);
            if (j == 0) slog[g] = acc;
        }
        __syncthreads();

        // softmax + ppi renorm on wave 0 (exact reference semantics)
        if (tid < KN) {
            float l = slog[tid] * 0.125f;     // scale = 64^-0.5
            float mx = l;
            #pragma unroll
            for (int off = 32; off >= 1; off >>= 1)
                mx = fmaxf(mx, __shfl_xor(mx, off, 64));
            float e = expf(l - mx);
            float se = e;
            #pragma unroll
            for (int off = 32; off >= 1; off >>= 1)
                se += __shfl_xor(se, off, 64);
            float pr = e / se;
            float t = pr * pv[r];
            float st = t;
            #pragma unroll
            for (int off = 32; off >= 1; off >>= 1)
                st += __shfl_xor(st, off, 64);
            sattn[tid] = t / (st + 1e-8f);
        }
        __syncthreads();

        // ctx: thread = (d-pair p, k-half h); sattn broadcast; scr combine
        {
            const int p = tid & 127, h = tid >> 7;
            float c0 = 0.f, c1 = 0.f;
            #pragma unroll
            for (int kk = 0; kk < 32; ++kk) {
                int k = h * 32 + kk;
                unsigned int nv = sn[k * 128 + p];
                float a = sattn[k];
                c0 += a * bf_lo(nv);
                c1 += a * bf_hi(nv);
            }
            if (h == 1) ((float2*)scr)[p] = make_float2(c0, c1);
            __syncthreads();
            if (h == 0) {
                float2 o = ((float2*)scr)[p];
                f32x2 res = {o.x + c0, o.y + c1};
                __builtin_nontemporal_store(res, (f32x2*)(ctx + (size_t)(b0 + r) * DN) + p);
            }
        }
    }
}

// ---------------------------------------------------------------------------
// K2: gate GEMM via MFMA bf16 + sigmoid blend (R7-verified).
// ---------------------------------------------------------------------------
__global__ __launch_bounds__(256) void gate_kernel(const float* __restrict__ center,
                                                   const float* __restrict__ ctxw,
                                                   const unsigned int* __restrict__ Wgb,
                                                   const float* __restrict__ bgate,
                                                   float* __restrict__ out) {
    __shared__ unsigned int xsb[32 * 260];   // 33.3 KB bf16 pairs: [cen 128 | ctx 128 | pad 4]
    const int r0 = blockIdx.x * 32;
    const int tid = threadIdx.x;

    const float4* c4 = (const float4*)(center + (size_t)r0 * DN);
    const float4* x4 = (const float4*)(ctxw + (size_t)r0 * DN);
    #pragma unroll
    for (int i = 0; i < 8; ++i) {
        int idx = tid + 256 * i;             // 0..2047
        int r = idx >> 6, c = idx & 63;
        float4 cv = c4[idx];
        float4 xv = x4[idx];
        *(uint2*)&xsb[r * 260 + 2 * c]       = make_uint2(pk2(cv.x, cv.y), pk2(cv.z, cv.w));
        *(uint2*)&xsb[r * 260 + 128 + 2 * c] = make_uint2(pk2(xv.x, xv.y), pk2(xv.z, xv.w));
    }
    __syncthreads();

    const int wave = tid >> 6, lane = tid & 63;
    const int l15 = lane & 15, lhi = lane >> 4;

    f32x4 acc[2][4];
    #pragma unroll
    for (int mt = 0; mt < 2; ++mt)
        #pragma unroll
        for (int nt = 0; nt < 4; ++nt)
            acc[mt][nt] = (f32x4){0.f, 0.f, 0.f, 0.f};

    #pragma unroll
    for (int ks = 0; ks < 16; ++ks) {        // K = 512 bf16, 32 per step
        s16x8 a0 = *(const s16x8*)&xsb[(l15)      * 260 + ks * 16 + lhi * 4];
        s16x8 a1 = *(const s16x8*)&xsb[(l15 + 16) * 260 + ks * 16 + lhi * 4];
        s16x8 b[4];
        #pragma unroll
        for (int nt = 0; nt < 4; ++nt) {
            int d = wave * 64 + nt * 16 + l15;
            b[nt] = *(const s16x8*)&Wgb[(size_t)d * 256 + ks * 16 + lhi * 4];
        }
        #pragma unroll
        for (int nt = 0; nt < 4; ++nt) {
            acc[0][nt] = __builtin_amdgcn_mfma_f32_16x16x32_bf16(a0, b[nt], acc[0][nt], 0, 0, 0);
            acc[1][nt] = __builtin_amdgcn_mfma_f32_16x16x32_bf16(a1, b[nt], acc[1][nt], 0, 0, 0);
        }
    }

    #pragma unroll
    for (int mt = 0; mt < 2; ++mt)
        #pragma unroll
        for (int nt = 0; nt < 4; ++nt) {
            int col = wave * 64 + nt * 16 + l15;
            float bg = bgate[col];
            #pragma unroll
            for (int reg = 0; reg < 4; ++reg) {
                int row = mt * 16 + lhi * 4 + reg;
                size_t gr = (size_t)(r0 + row);
                float z = acc[mt][nt][reg] + bg;
                float gt = 1.0f / (1.0f + expf(-z));
                float ce = center[gr * DN + col];   // f32, L2-warm
                float cx = ctxw[gr * DN + col];     // f32, L2-warm
                out[gr * DN + col] = gt * ce + (1.0f - gt) * cx;
            }
        }
}

// ---------------------------------------------------------------------------
extern "C" void kernel_launch(void* const* d_in, const int* in_sizes, int n_in,
                              void* d_out, int out_size, void* d_ws, size_t ws_size,
                              hipStream_t stream) {
    const float* center = (const float*)d_in[0];
    const float* neigh  = (const float*)d_in[1];
    const float* ppi    = (const float*)d_in[2];
    const float* Wq     = (const float*)d_in[3];
    const float* Wk     = (const float*)d_in[4];
    const float* Wgate  = (const float*)d_in[5];
    const float* bgate  = (const float*)d_in[6];
    float* out = (float*)d_out;

    char* ws = (char*)d_ws;
    float* M          = (float*)(ws);                            // 256 KB
    unsigned int* Wgb = (unsigned int*)(ws + 262144);            // 256 KB
    unsigned int* qkb = (unsigned int*)(ws + 524288);            // 8 MB bf16 pairs
    float* ctx        = (float*)(ws + 524288 + 8388608);         // 16 MB

    prep_kernel<<<dim3(512), dim3(256), 0, stream>>>(Wq, Wk, Wgate, M, Wgb);
    qk_kernel<<<dim3(B_N / 32), dim3(256), 0, stream>>>(center, M, qkb);
    attn_kernel<<<dim3(B_N / ROWS), dim3(256), 0, stream>>>(neigh, qkb, ppi, ctx);
    gate_kernel<<<dim3(B_N / 32), dim3(256), 0, stream>>>(center, ctx, Wgb, bgate, out);
}

// Round 12
// 255.483 us; speedup vs baseline: 1.0195x; 1.0195x over previous
//
#include <hip/hip_runtime.h>
#include <hip/hip_bf16.h>
#include <cstdint>

#define B_N 16384
#define KN 64
#define DN 256
#define AN 64
#define ROWS 4

typedef float f32x4 __attribute__((ext_vector_type(4)));
typedef float f32x2 __attribute__((ext_vector_type(2)));
typedef short s16x8 __attribute__((ext_vector_type(8)));

// pack two f32 -> one u32 of 2x bf16 (RTN); .x lands in low 16 bits
static __device__ inline unsigned int pk2(float a, float b) {
    __hip_bfloat162 h = __float22bfloat162_rn(make_float2(a, b));
    return *reinterpret_cast<unsigned int*>(&h);
}
static __device__ inline float bf_lo(unsigned int v) { return __uint_as_float(v << 16); }
static __device__ inline float bf_hi(unsigned int v) { return __uint_as_float(v & 0xFFFF0000u); }

// ---------------------------------------------------------------------------
// K0: M = Wq^T @ Wk (256x256 f32)  and  Wgb = bf16(Wgate) ([256 out][512 in])
// ---------------------------------------------------------------------------
__global__ __launch_bounds__(256) void prep_kernel(const float* __restrict__ Wq,
                                                   const float* __restrict__ Wk,
                                                   const float* __restrict__ Wgate,
                                                   float* __restrict__ M,
                                                   unsigned int* __restrict__ Wgb) {
    int blk = blockIdx.x;
    int t = threadIdx.x;
    if (blk < DN) {
        float acc = 0.f;
        #pragma unroll
        for (int a = 0; a < AN; ++a)
            acc += Wq[a * DN + blk] * Wk[a * DN + t];
        M[blk * DN + t] = acc;
    } else {
        int d = blk - DN;                    // 0..255 output row
        const float* src = Wgate + (size_t)d * (2 * DN);
        Wgb[(size_t)d * 256 + t] = pk2(src[2 * t], src[2 * t + 1]);
    }
}

// ---------------------------------------------------------------------------
// K0b: qk = center @ M, output bf16 pairs [B][128 words] (8 MB).
// M fully L2-resident here (no competing stream). R2-verified tile.
// ---------------------------------------------------------------------------
__global__ __launch_bounds__(256) void qk_kernel(const float* __restrict__ center,
                                                 const float* __restrict__ M,
                                                 unsigned int* __restrict__ qkb) {
    __shared__ float xs[32 * DN];            // 32 KB
    int r0 = blockIdx.x * 32;
    int tid = threadIdx.x;

    const float4* src = (const float4*)(center + (size_t)r0 * DN);
    float4* dst = (float4*)xs;
    #pragma unroll
    for (int i = 0; i < 8; ++i)
        dst[tid + 256 * i] = src[tid + 256 * i];
    __syncthreads();

    int ty = tid >> 5, tx = tid & 31;
    float acc[4][8];
    #pragma unroll
    for (int r = 0; r < 4; ++r)
        #pragma unroll
        for (int c = 0; c < 8; ++c) acc[r][c] = 0.f;

    for (int k4 = 0; k4 < DN; k4 += 4) {
        float4 xr[4];
        #pragma unroll
        for (int r = 0; r < 4; ++r)
            xr[r] = *(const float4*)(&xs[(ty * 4 + r) * DN + k4]);
        #pragma unroll
        for (int kk = 0; kk < 4; ++kk) {
            float4 ma = *(const float4*)(&M[(size_t)(k4 + kk) * DN + tx * 8]);
            float4 mb = *(const float4*)(&M[(size_t)(k4 + kk) * DN + tx * 8 + 4]);
            #pragma unroll
            for (int r = 0; r < 4; ++r) {
                float x = (&xr[r].x)[kk];
                acc[r][0] += x * ma.x; acc[r][1] += x * ma.y;
                acc[r][2] += x * ma.z; acc[r][3] += x * ma.w;
                acc[r][4] += x * mb.x; acc[r][5] += x * mb.y;
                acc[r][6] += x * mb.z; acc[r][7] += x * mb.w;
            }
        }
    }
    #pragma unroll
    for (int r = 0; r < 4; ++r) {
        size_t row = (size_t)(r0 + ty * 4 + r);
        uint4 o;
        o.x = pk2(acc[r][0], acc[r][1]);
        o.y = pk2(acc[r][2], acc[r][3]);
        o.z = pk2(acc[r][4], acc[r][5]);
        o.w = pk2(acc[r][6], acc[r][7]);
        *(uint4*)&qkb[row * 128 + tx * 4] = o;
    }
}

// ---------------------------------------------------------------------------
// K1: attention. 4096 blocks x 4 rows, ~35.3 KB LDS, launch_bounds(256,2)
// (verified; tighter caps spilled in R8/R9). 3 barriers/row:
// [guard] stage+prefetch [B1] logits [B2] softmax(all-wave redundant,
// per-wave sattn, no barrier) + one-d-per-thread ctx (no combine barrier).
// ---------------------------------------------------------------------------
__global__ __launch_bounds__(256, 2) void attn_kernel(const float* __restrict__ neigh,
                                                      const unsigned int* __restrict__ qkb,
                                                      const float* __restrict__ ppi,
                                                      float* __restrict__ ctx) {
    __shared__ unsigned int sn[KN * 128];    // 32 KB current tile (bf16 pairs)
    __shared__ unsigned int sqk[ROWS * 128]; //  2 KB q rows (bf16 pairs)
    __shared__ float slog[KN];               // 256 B logits
    __shared__ float sattn[4][KN];           //  1 KB per-wave attn copies

    const int tid = threadIdx.x;
    const int lane = tid & 63;
    const int wv = tid >> 6;
    const int b0 = blockIdx.x * ROWS;

    // issue row-0 tile prefetch (nontemporal: one-touch stream)
    f32x4 rr[16];
    {
        const f32x4* t4 = (const f32x4*)(neigh + (size_t)b0 * (KN * DN));
        #pragma unroll
        for (int i = 0; i < 16; ++i)
            rr[i] = __builtin_nontemporal_load(t4 + tid + 256 * i);
    }

    // qk rows -> LDS (512 words, one uint2 per thread)
    ((uint2*)sqk)[tid] = ((const uint2*)(qkb + (size_t)b0 * 128))[tid];

    // ppi rows -> registers (every wave keeps a copy; lane k holds ppi[k])
    float pv[ROWS];
    #pragma unroll
    for (int r = 0; r < ROWS; ++r) pv[r] = ppi[(size_t)(b0 + r) * KN + lane];

    #pragma unroll
    for (int r = 0; r < ROWS; ++r) {
        if (r > 0) __syncthreads();          // guard: prev row's ctx reads of sn done

        // staged regs -> sn (bf16 pairs)
        {
            uint2* dst = (uint2*)sn;
            #pragma unroll
            for (int i = 0; i < 16; ++i)
                dst[tid + 256 * i] = make_uint2(pk2(rr[i].x, rr[i].y), pk2(rr[i].z, rr[i].w));
        }
        // prefetch next row's tile (in flight during this row's compute)
        if (r < ROWS - 1) {
            const f32x4* n4 = (const f32x4*)(neigh + (size_t)(b0 + r + 1) * (KN * DN));
            #pragma unroll
            for (int i = 0; i < 16; ++i)
                rr[i] = __builtin_nontemporal_load(n4 + tid + 256 * i);
        }
        __syncthreads();                      // B1: sn (and for r=0: sqk) visible

        // logits: group g=tid>>2 owns k-row g; rotated d-walk (2-way banks)
        {
            const int g = tid >> 2, j = tid & 3;
            float acc = 0.f;
            #pragma unroll
            for (int m = 0; m < 32; ++m) {
                int s = (m + g) & 31;
                int p = j + 4 * s;            // pair index 0..127
                unsigned int nv = sn[g * 128 + p];
                unsigned int qv = sqk[r * 128 + p];
                acc += bf_lo(nv) * bf_lo(qv) + bf_hi(nv) * bf_hi(qv);
            }
            acc += __shfl_xor(acc, 1, 64);
            acc += __shfl_xor(acc, 2, 64);
            if (j == 0) slog[g] = acc;
        }
        __syncthreads();                      // B2: slog visible

        // softmax + ppi renorm: every wave redundantly (3 idle waves were
        // free); write own wave's sattn copy -> same-wave read, no barrier
        {
            float l = slog[lane] * 0.125f;    // scale = 64^-0.5
            float mx = l;
            #pragma unroll
            for (int off = 32; off >= 1; off >>= 1)
                mx = fmaxf(mx, __shfl_xor(mx, off, 64));
            float e = expf(l - mx);
            float se = e;
            #pragma unroll
            for (int off = 32; off >= 1; off >>= 1)
                se += __shfl_xor(se, off, 64);
            float t = (e / se) * pv[r];
            float st = t;
            #pragma unroll
            for (int off = 32; off >= 1; off >>= 1)
                st += __shfl_xor(st, off, 64);
            sattn[wv][lane] = t / (st + 1e-8f);
        }

        // ctx: one d per thread (d=tid); adjacent lanes share each sn word
        // (same-address broadcast, free); sattn read is wave-broadcast;
        // fully-coalesced f32 store
        {
            const int w = tid >> 1;
            const int sh = (tid & 1) ? 0 : 16;
            float c = 0.f;
            #pragma unroll
            for (int k = 0; k < KN; ++k) {
                unsigned int nv = sn[k * 128 + w];
                float xv = __uint_as_float((nv << sh) & 0xFFFF0000u);
                c += sattn[wv][k] * xv;
            }
            __builtin_nontemporal_store(c, ctx + (size_t)(b0 + r) * DN + tid);
        }
    }
}

// ---------------------------------------------------------------------------
// K2: gate GEMM via MFMA bf16 + sigmoid blend (R7-verified).
// ---------------------------------------------------------------------------
__global__ __launch_bounds__(256) void gate_kernel(const float* __restrict__ center,
                                                   const float* __restrict__ ctxw,
                                                   const unsigned int* __restrict__ Wgb,
                                                   const float* __restrict__ bgate,
                                                   float* __restrict__ out) {
    __shared__ unsigned int xsb[32 * 260];   // 33.3 KB bf16 pairs: [cen 128 | ctx 128 | pad 4]
    const int r0 = blockIdx.x * 32;
    const int tid = threadIdx.x;

    const float4* c4 = (const float4*)(center + (size_t)r0 * DN);
    const float4* x4 = (const float4*)(ctxw + (size_t)r0 * DN);
    #pragma unroll
    for (int i = 0; i < 8; ++i) {
        int idx = tid + 256 * i;             // 0..2047
        int r = idx >> 6, c = idx & 63;
        float4 cv = c4[idx];
        float4 xv = x4[idx];
        *(uint2*)&xsb[r * 260 + 2 * c]       = make_uint2(pk2(cv.x, cv.y), pk2(cv.z, cv.w));
        *(uint2*)&xsb[r * 260 + 128 + 2 * c] = make_uint2(pk2(xv.x, xv.y), pk2(xv.z, xv.w));
    }
    __syncthreads();

    const int wave = tid >> 6, lane = tid & 63;
    const int l15 = lane & 15, lhi = lane >> 4;

    f32x4 acc[2][4];
    #pragma unroll
    for (int mt = 0; mt < 2; ++mt)
        #pragma unroll
        for (int nt = 0; nt < 4; ++nt)
            acc[mt][nt] = (f32x4){0.f, 0.f, 0.f, 0.f};

    #pragma unroll
    for (int ks = 0; ks < 16; ++ks) {        // K = 512 bf16, 32 per step
        s16x8 a0 = *(const s16x8*)&xsb[(l15)      * 260 + ks * 16 + lhi * 4];
        s16x8 a1 = *(const s16x8*)&xsb[(l15 + 16) * 260 + ks * 16 + lhi * 4];
        s16x8 b[4];
        #pragma unroll
        for (int nt = 0; nt < 4; ++nt) {
            int d = wave * 64 + nt * 16 + l15;
            b[nt] = *(const s16x8*)&Wgb[(size_t)d * 256 + ks * 16 + lhi * 4];
        }
        #pragma unroll
        for (int nt = 0; nt < 4; ++nt) {
            acc[0][nt] = __builtin_amdgcn_mfma_f32_16x16x32_bf16(a0, b[nt], acc[0][nt], 0, 0, 0);
            acc[1][nt] = __builtin_amdgcn_mfma_f32_16x16x32_bf16(a1, b[nt], acc[1][nt], 0, 0, 0);
        }
    }

    #pragma unroll
    for (int mt = 0; mt < 2; ++mt)
        #pragma unroll
        for (int nt = 0; nt < 4; ++nt) {
            int col = wave * 64 + nt * 16 + l15;
            float bg = bgate[col];
            #pragma unroll
            for (int reg = 0; reg < 4; ++reg) {
                int row = mt * 16 + lhi * 4 + reg;
                size_t gr = (size_t)(r0 + row);
                float z = acc[mt][nt][reg] + bg;
                float gt = 1.0f / (1.0f + expf(-z));
                float ce = center[gr * DN + col];   // f32, L2-warm
                float cx = ctxw[gr * DN + col];     // f32, L2-warm
                out[gr * DN + col] = gt * ce + (1.0f - gt) * cx;
            }
        }
}

// ---------------------------------------------------------------------------
extern "C" void kernel_launch(void* const* d_in, const int* in_sizes, int n_in,
                              void* d_out, int out_size, void* d_ws, size_t ws_size,
                              hipStream_t stream) {
    const float* center = (const float*)d_in[0];
    const float* neigh  = (const float*)d_in[1];
    const float* ppi    = (const float*)d_in[2];
    const float* Wq     = (const float*)d_in[3];
    const float* Wk     = (const float*)d_in[4];
    const float* Wgate  = (const float*)d_in[5];
    const float* bgate  = (const float*)d_in[6];
    float* out = (float*)d_out;

    char* ws = (char*)d_ws;
    float* M          = (float*)(ws);                            // 256 KB
    unsigned int* Wgb = (unsigned int*)(ws + 262144);            // 256 KB
    unsigned int* qkb = (unsigned int*)(ws + 524288);            // 8 MB bf16 pairs
    float* ctx        = (float*)(ws + 524288 + 8388608);         // 16 MB

    prep_kernel<<<dim3(512), dim3(256), 0, stream>>>(Wq, Wk, Wgate, M, Wgb);
    qk_kernel<<<dim3(B_N / 32), dim3(256), 0, stream>>>(center, M, qkb);
    attn_kernel<<<dim3(B_N / ROWS), dim3(256), 0, stream>>>(neigh, qkb, ppi, ctx);
    gate_kernel<<<dim3(B_N / 32), dim3(256), 0, stream>>>(center, ctx, Wgb, bgate, out);
}